// Round 2
// baseline (1196.998 us; speedup 1.0000x reference)
//
#include <hip/hip_runtime.h>

// GRU stack, hidden_size=1, 6 layers, B=4096, T=2048, D=8.
// One 8-lane group per batch element: lanes 0..5 = layers (skewed pipeline),
// lanes 6..7 idle. Layer l at iteration i handles t = i - l; previous layer's
// h arrives via DPP row_shr:1 (lanes 0,16,32,48 cross rows but are all l==0,
// which ignore the neighbor).
//
// x is staged global->LDS with __builtin_amdgcn_global_load_lds in 16-step
// chunks (4 x 1KiB insts), double-buffered, counted s_waitcnt vmcnt(4) for a
// real one-chunk (~1000cy) prefetch distance. LDS layout [step][group][32B]
// is bank-conflict-free; in-group 8-lane reads of the same 32B broadcast.
//
// Gate math in exp2 form, constants pre-folded:
//   sigmoid(p) = rcp(1 + exp2(c1*p)),  c1 = -log2(e)
//   tanh(y)    = 2*rcp(1 + exp2(c2*y)) - 1,  c2 = -2*log2(e)

#define T_LEN 2048
#define T8    (T_LEN * 8)

__device__ __forceinline__ float dpp_shr1(float v) {
    int i = __builtin_bit_cast(int, v);
    int r = __builtin_amdgcn_update_dpp(0, i, 0x111 /*row_shr:1*/, 0xF, 0xF, true);
    return __builtin_bit_cast(float, r);
}

__device__ __forceinline__ void gload_lds(const float* g, float* l) {
    __builtin_amdgcn_global_load_lds(
        (const __attribute__((address_space(1))) void*)g,
        (__attribute__((address_space(3))) void*)l, 16, 0, 0);
}

__launch_bounds__(64, 1)
__global__ void gru_scan(const float* __restrict__ x,
                         const float* __restrict__ Wih0,   // [3][8]
                         const float* __restrict__ Wrest,  // [5][3]
                         const float* __restrict__ Whh,    // [6][3]
                         const float* __restrict__ bih,    // [6][3]
                         const float* __restrict__ bhh,    // [6][3]
                         float* __restrict__ out)          // [B]
{
    __shared__ float lds[2048];          // 2 buffers x 1024 floats (4KB each)

    const int lane = threadIdx.x;        // 0..63, block = 1 wave
    const int l    = lane & 7;           // 0..5 layers, 6..7 idle
    const int g    = lane >> 3;          // group (batch) within wave
    const int b    = blockIdx.x * 8 + g;

    const float c1 = -1.44269504088896340736f;   // -log2(e)
    const float c2 = 2.0f * c1;

    const int  lidx = l < 6 ? l : 5;
    const bool lz   = (l == 0);
    const float m1  = lz ? 0.0f : 1.0f;  // zero the nbr weight on layer 0

    const float whpr = c1 * Whh[lidx * 3 + 0];
    const float whpz = c1 * Whh[lidx * 3 + 1];
    const float whpn = c2 * Whh[lidx * 3 + 2];
    const float bhpn = c2 * bhh[lidx * 3 + 2];

    const int ir = lidx >= 1 ? lidx - 1 : 0;
    const float W1r = m1 * c1 * Wrest[ir * 3 + 0];
    const float W1z = m1 * c1 * Wrest[ir * 3 + 1];
    const float W1n = m1 * c2 * Wrest[ir * 3 + 2];
    const float B1r = c1 * (bih[lidx * 3 + 0] + bhh[lidx * 3 + 0]);
    const float B1z = c1 * (bih[lidx * 3 + 1] + bhh[lidx * 3 + 1]);
    const float B1n = c2 *  bih[lidx * 3 + 2];

    // layer-0 projection weights, pre-scaled (uniform)
    float wr[8], wz[8], wn[8];
    #pragma unroll
    for (int d = 0; d < 8; ++d) {
        wr[d] = c1 * Wih0[d];
        wz[d] = c1 * Wih0[8 + d];
        wn[d] = c2 * Wih0[16 + d];
    }

    // staging source: lane covers (group sg, step-slot ssl, half sof) of a chunk
    const int sg  = (lane & 15) >> 1;    // 0..7
    const int ssl = lane >> 4;           // 0..3
    const int sof = (lane & 1) * 4;      // 0 or 4 floats
    const float* sp = x + (size_t)(blockIdx.x * 8 + sg) * T8 + (size_t)ssl * 8 + sof;

    float h = 0.0f;

    auto stage = [&](int c) {
        const float* p = sp + (size_t)c * 128;   // 16 steps * 8 floats
        float* d = &lds[(c & 1) * 1024];
        gload_lds(p,      d);
        gload_lds(p + 32, d + 256);
        gload_lds(p + 64, d + 512);
        gload_lds(p + 96, d + 768);
    };

    auto step = [&](int i, float4 xa, float4 xb, bool guard) {
        const float nbr = dpp_shr1(h);   // prev layer's h (post step i-1)

        // layer-0 projection (all lanes compute; only l==0 consumes)
        float pr = B1r, pz = B1z, pn = B1n;
        pr = fmaf(xa.x, wr[0], pr); pr = fmaf(xa.y, wr[1], pr);
        pr = fmaf(xa.z, wr[2], pr); pr = fmaf(xa.w, wr[3], pr);
        pr = fmaf(xb.x, wr[4], pr); pr = fmaf(xb.y, wr[5], pr);
        pr = fmaf(xb.z, wr[6], pr); pr = fmaf(xb.w, wr[7], pr);
        pz = fmaf(xa.x, wz[0], pz); pz = fmaf(xa.y, wz[1], pz);
        pz = fmaf(xa.z, wz[2], pz); pz = fmaf(xa.w, wz[3], pz);
        pz = fmaf(xb.x, wz[4], pz); pz = fmaf(xb.y, wz[5], pz);
        pz = fmaf(xb.z, wz[6], pz); pz = fmaf(xb.w, wz[7], pz);
        pn = fmaf(xa.x, wn[0], pn); pn = fmaf(xa.y, wn[1], pn);
        pn = fmaf(xa.z, wn[2], pn); pn = fmaf(xa.w, wn[3], pn);
        pn = fmaf(xb.x, wn[4], pn); pn = fmaf(xb.y, wn[5], pn);
        pn = fmaf(xb.z, wn[6], pn); pn = fmaf(xb.w, wn[7], pn);

        // bias/projection base, selected OFF the h-chain
        const float br = lz ? pr : B1r;
        const float bz = lz ? pz : B1z;
        const float bn = lz ? pn : B1n;

        const float ar = fmaf(whpr, h, fmaf(W1r, nbr, br));
        const float er = __builtin_amdgcn_exp2f(ar);
        const float r  = __builtin_amdgcn_rcpf(1.0f + er);
        const float az = fmaf(whpz, h, fmaf(W1z, nbr, bz));
        const float ez = __builtin_amdgcn_exp2f(az);
        const float z  = __builtin_amdgcn_rcpf(1.0f + ez);
        const float xnp = fmaf(W1n, nbr, bn);
        const float tn  = fmaf(whpn, h, bhpn);
        const float en  = __builtin_amdgcn_exp2f(fmaf(r, tn, xnp));
        const float dd  = __builtin_amdgcn_rcpf(1.0f + en);

        const float omz  = 1.0f - z;
        const float omz2 = omz + omz;
        const float bse  = fmaf(z, h, -omz);
        const float hn   = fmaf(omz2, dd, bse);   // (1-z)*tanh + z*h

        if (guard) {
            h = ((unsigned)(i - l) < (unsigned)T_LEN) ? hn : h;
        } else {
            h = hn;
        }
    };

    auto run_chunk = [&](int c, bool guard) {
        const int buf = (c & 1) * 1024;
        #pragma unroll
        for (int s = 0; s < 16; ++s) {
            const int idx = buf + s * 64 + g * 8;
            const float4 xa = *reinterpret_cast<const float4*>(&lds[idx]);
            const float4 xb = *reinterpret_cast<const float4*>(&lds[idx + 4]);
            step(c * 16 + s, xa, xb, guard);
        }
    };

    stage(0);
    stage(1);

    asm volatile("s_waitcnt vmcnt(4)" ::: "memory");   // chunk 0 landed
    run_chunk(0, true);                                 // guarded (t<0 lanes)
    asm volatile("s_waitcnt lgkmcnt(0)" ::: "memory"); // reads retired
    stage(2);

    #pragma unroll 1
    for (int c = 1; c <= 125; ++c) {
        asm volatile("s_waitcnt vmcnt(4)" ::: "memory");   // chunk c landed
        run_chunk(c, false);
        asm volatile("s_waitcnt lgkmcnt(0)" ::: "memory");
        stage(c + 2);
    }

    asm volatile("s_waitcnt vmcnt(4)" ::: "memory");
    run_chunk(126, false);
    asm volatile("s_waitcnt vmcnt(0)" ::: "memory");
    run_chunk(127, false);

    // tail: 5 guarded steps, no x (zero proj input -> base = bias, l==0 frozen)
    const float4 zf = make_float4(0.f, 0.f, 0.f, 0.f);
    #pragma unroll
    for (int i = T_LEN; i < T_LEN + 5; ++i) step(i, zf, zf, true);

    if (l == 5) out[b] = h;   // layer-5 h frozen at t = T-1
}

extern "C" void kernel_launch(void* const* d_in, const int* in_sizes, int n_in,
                              void* d_out, int out_size, void* d_ws, size_t ws_size,
                              hipStream_t stream) {
    const float* x     = (const float*)d_in[0];
    const float* Wih0  = (const float*)d_in[1];
    const float* Wrest = (const float*)d_in[2];
    const float* Whh   = (const float*)d_in[3];
    const float* bih   = (const float*)d_in[4];
    const float* bhh   = (const float*)d_in[5];
    float* out = (float*)d_out;

    gru_scan<<<512, 64, 0, stream>>>(x, Wih0, Wrest, Whh, bih, bhh, out);
}